// Round 7
// baseline (107.628 us; speedup 1.0000x reference)
//
#include <hip/hip_runtime.h>
#include <math.h>

#define Bg 256
#define Nn 4096
#define Ee 65536
#define Kk (Nn * 3)   // 12288

__device__ __forceinline__ unsigned bf16r(float v) {   // fp32 -> bf16 bits, RNE
    unsigned b = __float_as_uint(v);
    return (b + 0x7fffu + ((b >> 16) & 1u)) >> 16;
}

// ---------------- fused edge-prep + raw-bf16 transpose (independent halves) ----------------
// bid <  256 : edge prep — deg_out histogram + capacity-64 CSR by dst
// bid >= 256 : transpose x -> bf16-packed superslabs of 128 batches
//              xsb[bq][n][bl] (bq in [0,2), bl in [0,128)), uint2 per (n,bl)
__global__ __launch_bounds__(256) void k_pt(const float* __restrict__ x,
                                            const int* __restrict__ src,
                                            const int* __restrict__ dst,
                                            int* __restrict__ deg_out,
                                            int* __restrict__ cursor,
                                            int* __restrict__ csr,
                                            uint2* __restrict__ xsb) {
    __shared__ float4 tile4[64][49];           // row stride 196 floats
    const int t = threadIdx.x;
    const int bid = blockIdx.x;
    if (bid < 256) {                           // ---- prep half ----
        int e = bid * 256 + t;
        int s = src[e], d = dst[e];
        atomicAdd(&deg_out[s], 1);
        int ofs = atomicAdd(&cursor[d], 1) & 63;   // capacity 64 (max in-deg ~35 << 64)
        csr[(d << 6) + ofs] = s;
        return;
    }
    const int bt = bid - 256;                  // ---- transpose half ----
    const int ni = bt & 63, bc = bt >> 6;      // node tile, batch chunk of 64
    const int n0 = ni * 64;
    const float* xb = x + (size_t)bc * 64 * Kk + (size_t)n0 * 3;
#pragma unroll
    for (int i = 0; i < 12; i++) {
        int idx = i * 256 + t;
        int bi = idx / 48, j = idx - bi * 48;
        tile4[bi][j] = ((const float4*)(xb + (size_t)bi * Kk))[j];
    }
    __syncthreads();
    const float* tile = (const float*)tile4;   // [64][196]
    // batch chunk bc -> superslab bc>>1, half (bc&1)*64
    uint2* outp = xsb + ((size_t)(bc >> 1) * Nn + n0) * 128 + (bc & 1) * 64;
#pragma unroll
    for (int i = 0; i < 16; i++) {
        int idx = i * 256 + t;
        int nn = idx >> 6, bl = idx & 63;      // per wave: nn fixed, bl = lane
        float f0 = tile[bl * 196 + nn * 3 + 0];
        float f1 = tile[bl * 196 + nn * 3 + 1];
        float f2 = tile[bl * 196 + nn * 3 + 2];
        uint2 u;
        u.x = bf16r(f0) | (bf16r(f1) << 16);
        u.y = bf16r(f2);
        outp[(size_t)nn * 128 + bl] = u;
    }
}

// ---------------- fused gather + (3->64) matmul + relu + Wfc dot ----------------
// 4 waves/block, ONE node per wave, TWO batch elements per lane (dwordx4 gather).
// Edge list held IN REGISTERS: lane t owns slot t (one coalesced 256 B load);
// per-edge broadcast via v_readlane (SGPR lane index — ~free ALU op, no LDS pipe,
// no s_load latency chain). Only memory op per edge is the slab gather itself.
__global__ __launch_bounds__(256) void k_main(const uint2* __restrict__ xsb,
                                              const float* __restrict__ W1,
                                              const float* __restrict__ b1,
                                              const float* __restrict__ Wfc,
                                              const int* __restrict__ deg_out,
                                              const int* __restrict__ cursor,
                                              const int* __restrict__ csr,
                                              float* __restrict__ partial) {
    __shared__ float4 sW14[64];
    __shared__ float sWfc[4][64];
    __shared__ float2 red[4][64];
    const int t = threadIdx.x & 63;
    const int w = threadIdx.x >> 6;
    const int bq = blockIdx.x & 1;      // superslab; XCD i (bid%8) sees bq=i&1 -> L2-resident
    const int g  = blockIdx.x >> 1;     // node group [0,1024)
    const int n  = __builtin_amdgcn_readfirstlane(g * 4 + w);   // provably wave-uniform
    if (w == 0) sW14[t] = make_float4(W1[t], W1[64 + t], W1[128 + t], b1[t]);
    sWfc[w][t] = Wfc[n * 64 + t];
    __syncthreads();

    // lane t covers batches (bq*128 + 2t, +2t+1): one uint4 = 16 B per edge
    const uint4* __restrict__ slab = (const uint4*)xsb + (size_t)bq * (Nn * 64);
    int myedge = csr[(n << 6) + t] & (Nn - 1);   // whole row in one wave load; mask poison
    unsigned mycs = __float_as_uint(rsqrtf(fmaxf((float)deg_out[myedge], 1.0f)));
    int deg = cursor[n]; if (deg > 64) deg = 64;
    deg = __builtin_amdgcn_readfirstlane(deg);   // uniform loop bound
    float a0 = 0.f, a1 = 0.f, a2 = 0.f, a3 = 0.f, a4 = 0.f, a5 = 0.f;
    float c0 = 0.f, c1 = 0.f, c2 = 0.f, c3 = 0.f, c4 = 0.f, c5 = 0.f;
    int i = 0;
#pragma unroll 2
    for (; i + 2 <= deg; i += 2) {
        int   s0 = __builtin_amdgcn_readlane(myedge, i);          // SALU broadcast, no mem
        int   s1 = __builtin_amdgcn_readlane(myedge, i + 1);
        float q0 = __uint_as_float(__builtin_amdgcn_readlane(mycs, i));
        float q1 = __uint_as_float(__builtin_amdgcn_readlane(mycs, i + 1));
        uint4 u0 = slab[(s0 << 6) + t];                           // SGPR base + lane offset
        uint4 u1 = slab[(s1 << 6) + t];
        a0 = fmaf(q0, __uint_as_float(u0.x << 16), a0);
        a1 = fmaf(q0, __uint_as_float(u0.x & 0xffff0000u), a1);
        a2 = fmaf(q0, __uint_as_float(u0.y << 16), a2);
        a3 = fmaf(q0, __uint_as_float(u0.z << 16), a3);
        a4 = fmaf(q0, __uint_as_float(u0.z & 0xffff0000u), a4);
        a5 = fmaf(q0, __uint_as_float(u0.w << 16), a5);
        c0 = fmaf(q1, __uint_as_float(u1.x << 16), c0);
        c1 = fmaf(q1, __uint_as_float(u1.x & 0xffff0000u), c1);
        c2 = fmaf(q1, __uint_as_float(u1.y << 16), c2);
        c3 = fmaf(q1, __uint_as_float(u1.z << 16), c3);
        c4 = fmaf(q1, __uint_as_float(u1.z & 0xffff0000u), c4);
        c5 = fmaf(q1, __uint_as_float(u1.w << 16), c5);
    }
    if (i < deg) {
        int   s = __builtin_amdgcn_readlane(myedge, i);
        float q = __uint_as_float(__builtin_amdgcn_readlane(mycs, i));
        uint4 u = slab[(s << 6) + t];
        a0 = fmaf(q, __uint_as_float(u.x << 16), a0);
        a1 = fmaf(q, __uint_as_float(u.x & 0xffff0000u), a1);
        a2 = fmaf(q, __uint_as_float(u.y << 16), a2);
        a3 = fmaf(q, __uint_as_float(u.z << 16), a3);
        a4 = fmaf(q, __uint_as_float(u.z & 0xffff0000u), a4);
        a5 = fmaf(q, __uint_as_float(u.w << 16), a5);
    }
    a0 += c0; a1 += c1; a2 += c2; a3 += c3; a4 += c4; a5 += c5;
    float cd = rsqrtf(fmaxf((float)deg, 1.0f));
    a0 *= cd; a1 *= cd; a2 *= cd; a3 *= cd; a4 *= cd; a5 *= cd;

    float pe = 0.f, po = 0.f;
#pragma unroll 8
    for (int f = 0; f < 64; f++) {
        float4 wv = sW14[f];
        float he = fmaf(a0, wv.x, fmaf(a1, wv.y, fmaf(a2, wv.z, wv.w)));
        float ho = fmaf(a3, wv.x, fmaf(a4, wv.y, fmaf(a5, wv.z, wv.w)));
        float wf = sWfc[w][f];
        pe = fmaf(fmaxf(he, 0.f), wf, pe);
        po = fmaf(fmaxf(ho, 0.f), wf, po);
    }
    red[w][t].x = pe;
    red[w][t].y = po;
    __syncthreads();
    if (w == 0) {
        float2 r0 = red[0][t], r1 = red[1][t], r2 = red[2][t], r3 = red[3][t];
        float2 tot;
        tot.x = (r0.x + r1.x) + (r2.x + r3.x);
        tot.y = (r0.y + r1.y) + (r2.y + r3.y);
        // batches bq*128+2t, +2t+1 of group g -> partial[g*256 + b] (layout as v5)
        ((float2*)partial)[(g << 7) + (bq << 6) + t] = tot;
    }
}

// ---------------- tail: coalesced reduce over 1024 groups + last-block sigmoid ----------------
// 64 blocks x 16 groups each; one atomicAdd round (64 per address); fence runs 64x only.
__global__ __launch_bounds__(256) void k_tail(const float* __restrict__ partial,
                                              const float* __restrict__ bfc,
                                              float* __restrict__ out_acc,
                                              int* __restrict__ done,
                                              float* __restrict__ out) {
    __shared__ int lastblk;
    const int t = threadIdx.x;
    const int g0 = blockIdx.x * 16;
    float s = 0.f;
#pragma unroll
    for (int g = 0; g < 16; g++) s += partial[((g0 + g) << 8) + t];   // coalesced
    atomicAdd(&out_acc[t], s);
    __threadfence();
    __syncthreads();
    if (t == 0) lastblk = (atomicAdd(done, 1) == (int)gridDim.x - 1);
    __syncthreads();
    if (lastblk) {
        float v = atomicAdd(&out_acc[t], 0.0f) + bfc[0];   // coherent read
        out[t] = 1.0f / (1.0f + expf(-v));
    }
}

extern "C" void kernel_launch(void* const* d_in, const int* in_sizes, int n_in,
                              void* d_out, int out_size, void* d_ws, size_t ws_size,
                              hipStream_t stream) {
    const float* x   = (const float*)d_in[0];
    const float* W1  = (const float*)d_in[1];
    const float* b1  = (const float*)d_in[2];
    const float* Wfc = (const float*)d_in[3];
    const float* bfc = (const float*)d_in[4];
    const int*   src = (const int*)d_in[5];
    const int*   dst = (const int*)d_in[6];
    float* out = (float*)d_out;

    char* ws = (char*)d_ws;
    uint2* xsb = (uint2*)ws;                       // 2 superslabs x 4 MB = 8,388,608 B
    const size_t Z = (size_t)2 * Nn * 128 * 8;
    int*   deg_out = (int*)(ws + Z);               // 16 KB (zeroed)
    int*   cursor  = (int*)(ws + Z + 16384);       // 16 KB (zeroed)
    float* out_acc = (float*)(ws + Z + 32768);     // 1 KB  (zeroed)
    int*   done    = (int*)(ws + Z + 33792);       // 4 B   (zeroed)
    int*   csr     = (int*)(ws + Z + 34048);       // 4096*64 ints = 1 MB
    float* partial = (float*)(ws + Z + 34048 + 1048576);   // 1 MB

    hipMemsetAsync(ws + Z, 0, 34048, stream);
    k_pt<<<512, 256, 0, stream>>>(x, src, dst, deg_out, cursor, csr, xsb);
    k_main<<<1024 * 2, 256, 0, stream>>>(xsb, W1, b1, Wfc, deg_out, cursor, csr, partial);
    k_tail<<<64, 256, 0, stream>>>(partial, bfc, out_acc, done, out);
}

// Round 8
// 105.239 us; speedup vs baseline: 1.0227x; 1.0227x over previous
//
#include <hip/hip_runtime.h>
#include <math.h>

#define Bg 256
#define Nn 4096
#define Ee 65536
#define Kk (Nn * 3)   // 12288

__device__ __forceinline__ unsigned bf16r(float v) {   // fp32 -> bf16 bits, RNE
    unsigned b = __float_as_uint(v);
    return (b + 0x7fffu + ((b >> 16) & 1u)) >> 16;
}

// ---------------- fused edge-prep + raw-bf16 transpose (independent halves) ----------------
// bid <  256 : edge prep — deg_out histogram + capacity-64 CSR by dst
// bid >= 256 : transpose x -> bf16-packed superslabs of 128 batches.
// Transpose stages PACKED uint2 through an XOR-swizzled [64][64] tile:
//   write tile[nn][bi^nn] (lane=nn), read tile[nn][bl^nn] (lane=bl) — both at the
//   structural bank minimum (old layout was ~8-way conflicted on both phases).
__global__ __launch_bounds__(256) void k_pt(const float* __restrict__ x,
                                            const int* __restrict__ src,
                                            const int* __restrict__ dst,
                                            int* __restrict__ deg_out,
                                            int* __restrict__ cursor,
                                            int* __restrict__ csr,
                                            uint2* __restrict__ xsb) {
    __shared__ uint2 tile[64][64];             // 32 KB, XOR-swizzled cells
    const int t = threadIdx.x;
    const int bid = blockIdx.x;
    if (bid < 256) {                           // ---- prep half ----
        int e = bid * 256 + t;
        int s = src[e], d = dst[e];
        atomicAdd(&deg_out[s], 1);
        int ofs = atomicAdd(&cursor[d], 1) & 63;   // capacity 64 (max in-deg ~35 << 64)
        csr[(d << 6) + ofs] = s;
        return;
    }
    const int bt = bid - 256;                  // ---- transpose half ----
    const int ni = bt & 63, bc = bt >> 6;      // node tile, batch chunk of 64
    const int n0 = ni * 64;
    const float* xb = x + (size_t)bc * 64 * Kk + (size_t)n0 * 3;
#pragma unroll
    for (int i = 0; i < 16; i++) {             // lane: one (batch bi, node nn) triplet
        int idx = i * 256 + t;
        int bi = idx >> 6, nn = idx & 63;      // per wave: bi fixed, nn = lane -> coalesced
        const float* p = xb + (size_t)bi * Kk + nn * 3;
        float f0 = p[0], f1 = p[1], f2 = p[2]; // 12 B/lane, contiguous 768 B/wave
        uint2 u;
        u.x = bf16r(f0) | (bf16r(f1) << 16);
        u.y = bf16r(f2);
        tile[nn][bi ^ nn] = u;                 // XOR swizzle: bank-minimal write
    }
    __syncthreads();
    // batch chunk bc -> superslab bc>>1, half (bc&1)*64
    uint2* outp = xsb + ((size_t)(bc >> 1) * Nn + n0) * 128 + (bc & 1) * 64;
#pragma unroll
    for (int i = 0; i < 16; i++) {
        int idx = i * 256 + t;
        int nn = idx >> 6, bl = idx & 63;      // per wave: nn fixed, bl = lane
        uint2 u = tile[nn][bl ^ nn];           // bank-minimal read
        outp[(size_t)nn * 128 + bl] = u;       // coalesced 512 B/wave store
    }
}

// ---------------- fused gather + (3->64) matmul + relu + Wfc dot ----------------
// v6 k_main VERBATIM (measured best, 105.5): 4 waves/block, ONE node per wave,
// TWO batch elements per lane (dwordx4 gather). Edge walk wave-uniform via
// readfirstlane -> edge ids / deg / cs ride the scalar pipe.
__global__ __launch_bounds__(256) void k_main(const uint2* __restrict__ xsb,
                                              const float* __restrict__ W1,
                                              const float* __restrict__ b1,
                                              const float* __restrict__ Wfc,
                                              const int* __restrict__ deg_out,
                                              const int* __restrict__ cursor,
                                              const int* __restrict__ csr,
                                              float* __restrict__ partial) {
    __shared__ float4 sW14[64];
    __shared__ float sWfc[4][64];
    __shared__ float2 red[4][64];
    const int t = threadIdx.x & 63;
    const int w = threadIdx.x >> 6;
    const int bq = blockIdx.x & 1;      // superslab; XCD i (bid%8) sees bq=i&1 -> L2-resident
    const int g  = blockIdx.x >> 1;     // node group [0,1024)
    const int n  = __builtin_amdgcn_readfirstlane(g * 4 + w);   // provably wave-uniform
    if (w == 0) sW14[t] = make_float4(W1[t], W1[64 + t], W1[128 + t], b1[t]);
    sWfc[w][t] = Wfc[n * 64 + t];
    __syncthreads();

    // lane t covers batches (bq*128 + 2t, +2t+1): one uint4 = 16 B per edge
    const uint4* __restrict__ slab = (const uint4*)xsb + (size_t)bq * (Nn * 64);
    const int* __restrict__ crow = csr + (n << 6);
    int deg = cursor[n]; if (deg > 64) deg = 64;            // uniform
    float a0 = 0.f, a1 = 0.f, a2 = 0.f, a3 = 0.f, a4 = 0.f, a5 = 0.f;
    float c0 = 0.f, c1 = 0.f, c2 = 0.f, c3 = 0.f, c4 = 0.f, c5 = 0.f;
    int i = 0;
#pragma unroll 2
    for (; i + 2 <= deg; i += 2) {
        int s0 = crow[i], s1 = crow[i + 1];                 // uniform -> scalar pipe
        float q0 = rsqrtf(fmaxf((float)deg_out[s0], 1.0f)); // uniform load, cheap math
        float q1 = rsqrtf(fmaxf((float)deg_out[s1], 1.0f));
        uint4 u0 = slab[(s0 << 6) + t];                     // SGPR base + lane offset
        uint4 u1 = slab[(s1 << 6) + t];
        a0 = fmaf(q0, __uint_as_float(u0.x << 16), a0);
        a1 = fmaf(q0, __uint_as_float(u0.x & 0xffff0000u), a1);
        a2 = fmaf(q0, __uint_as_float(u0.y << 16), a2);
        a3 = fmaf(q0, __uint_as_float(u0.z << 16), a3);
        a4 = fmaf(q0, __uint_as_float(u0.z & 0xffff0000u), a4);
        a5 = fmaf(q0, __uint_as_float(u0.w << 16), a5);
        c0 = fmaf(q1, __uint_as_float(u1.x << 16), c0);
        c1 = fmaf(q1, __uint_as_float(u1.x & 0xffff0000u), c1);
        c2 = fmaf(q1, __uint_as_float(u1.y << 16), c2);
        c3 = fmaf(q1, __uint_as_float(u1.z << 16), c3);
        c4 = fmaf(q1, __uint_as_float(u1.z & 0xffff0000u), c4);
        c5 = fmaf(q1, __uint_as_float(u1.w << 16), c5);
    }
    if (i < deg) {
        int s = crow[i];
        float q = rsqrtf(fmaxf((float)deg_out[s], 1.0f));
        uint4 u = slab[(s << 6) + t];
        a0 = fmaf(q, __uint_as_float(u.x << 16), a0);
        a1 = fmaf(q, __uint_as_float(u.x & 0xffff0000u), a1);
        a2 = fmaf(q, __uint_as_float(u.y << 16), a2);
        a3 = fmaf(q, __uint_as_float(u.z << 16), a3);
        a4 = fmaf(q, __uint_as_float(u.z & 0xffff0000u), a4);
        a5 = fmaf(q, __uint_as_float(u.w << 16), a5);
    }
    a0 += c0; a1 += c1; a2 += c2; a3 += c3; a4 += c4; a5 += c5;
    float cd = rsqrtf(fmaxf((float)deg, 1.0f));
    a0 *= cd; a1 *= cd; a2 *= cd; a3 *= cd; a4 *= cd; a5 *= cd;

    float pe = 0.f, po = 0.f;
#pragma unroll 8
    for (int f = 0; f < 64; f++) {
        float4 wv = sW14[f];
        float he = fmaf(a0, wv.x, fmaf(a1, wv.y, fmaf(a2, wv.z, wv.w)));
        float ho = fmaf(a3, wv.x, fmaf(a4, wv.y, fmaf(a5, wv.z, wv.w)));
        float wf = sWfc[w][f];
        pe = fmaf(fmaxf(he, 0.f), wf, pe);
        po = fmaf(fmaxf(ho, 0.f), wf, po);
    }
    red[w][t].x = pe;
    red[w][t].y = po;
    __syncthreads();
    if (w == 0) {
        float2 r0 = red[0][t], r1 = red[1][t], r2 = red[2][t], r3 = red[3][t];
        float2 tot;
        tot.x = (r0.x + r1.x) + (r2.x + r3.x);
        tot.y = (r0.y + r1.y) + (r2.y + r3.y);
        // batches bq*128+2t, +2t+1 of group g -> partial[g*256 + b] (layout as v5)
        ((float2*)partial)[(g << 7) + (bq << 6) + t] = tot;
    }
}

// ---------------- tail: coalesced reduce over 1024 groups + last-block sigmoid ----------------
// 64 blocks x 16 groups each; one atomicAdd round (64 per address); fence runs 64x only.
__global__ __launch_bounds__(256) void k_tail(const float* __restrict__ partial,
                                              const float* __restrict__ bfc,
                                              float* __restrict__ out_acc,
                                              int* __restrict__ done,
                                              float* __restrict__ out) {
    __shared__ int lastblk;
    const int t = threadIdx.x;
    const int g0 = blockIdx.x * 16;
    float s = 0.f;
#pragma unroll
    for (int g = 0; g < 16; g++) s += partial[((g0 + g) << 8) + t];   // coalesced
    atomicAdd(&out_acc[t], s);
    __threadfence();
    __syncthreads();
    if (t == 0) lastblk = (atomicAdd(done, 1) == (int)gridDim.x - 1);
    __syncthreads();
    if (lastblk) {
        float v = atomicAdd(&out_acc[t], 0.0f) + bfc[0];   // coherent read
        out[t] = 1.0f / (1.0f + expf(-v));
    }
}

extern "C" void kernel_launch(void* const* d_in, const int* in_sizes, int n_in,
                              void* d_out, int out_size, void* d_ws, size_t ws_size,
                              hipStream_t stream) {
    const float* x   = (const float*)d_in[0];
    const float* W1  = (const float*)d_in[1];
    const float* b1  = (const float*)d_in[2];
    const float* Wfc = (const float*)d_in[3];
    const float* bfc = (const float*)d_in[4];
    const int*   src = (const int*)d_in[5];
    const int*   dst = (const int*)d_in[6];
    float* out = (float*)d_out;

    char* ws = (char*)d_ws;
    uint2* xsb = (uint2*)ws;                       // 2 superslabs x 4 MB = 8,388,608 B
    const size_t Z = (size_t)2 * Nn * 128 * 8;
    int*   deg_out = (int*)(ws + Z);               // 16 KB (zeroed)
    int*   cursor  = (int*)(ws + Z + 16384);       // 16 KB (zeroed)
    float* out_acc = (float*)(ws + Z + 32768);     // 1 KB  (zeroed)
    int*   done    = (int*)(ws + Z + 33792);       // 4 B   (zeroed)
    int*   csr     = (int*)(ws + Z + 34048);       // 4096*64 ints = 1 MB
    float* partial = (float*)(ws + Z + 34048 + 1048576);   // 1 MB

    hipMemsetAsync(ws + Z, 0, 34048, stream);
    k_pt<<<512, 256, 0, stream>>>(x, src, dst, deg_out, cursor, csr, xsb);
    k_main<<<1024 * 2, 256, 0, stream>>>(xsb, W1, b1, Wfc, deg_out, cursor, csr, partial);
    k_tail<<<64, 256, 0, stream>>>(partial, bfc, out_acc, done, out);
}